// Round 8
// baseline (1122.514 us; speedup 1.0000x reference)
//
#include <hip/hip_runtime.h>

#define N_NODES 10000
#define NV_PAD  10048
#define N_EDGES 50000
#define IN0     32
#define EDGE_IN 16
#define GIN     8
#define HID     64
#define NG      64
#define KDIM    128
#define NCOL    8192
#define EPS     1e-5f

typedef _Float16 f16;
typedef _Float16 v8h __attribute__((ext_vector_type(8)));
typedef float    v4f __attribute__((ext_vector_type(4)));

// ---------------------------------------------------------------------------
// h[e][j] = relu(ea[e]@w1[:,j] + b1[j])   fp32, row-major [E,128]
__global__ __launch_bounds__(256) void h_kernel(const float* __restrict__ ea,
                                                const float* __restrict__ w1,
                                                const float* __restrict__ b1,
                                                float* __restrict__ h) {
    size_t idx = (size_t)blockIdx.x * 256 + threadIdx.x;
    if (idx >= (size_t)N_EDGES * KDIM) return;
    int j = (int)(idx & 127);
    size_t e = idx >> 7;
    const float* ear = ea + e * EDGE_IN;
    float acc = b1[j];
#pragma unroll
    for (int t = 0; t < EDGE_IN; t++) acc += ear[t] * w1[t * KDIM + j];
    h[idx] = fmaxf(acc, 0.f);
}

// ---------------------------------------------------------------------------
// Edge sorting by src: histogram -> scan -> scatter (once per call)
__global__ __launch_bounds__(256) void hist_kernel(const int* __restrict__ src,
                                                   int* __restrict__ cnt) {
    int e = blockIdx.x * 256 + threadIdx.x;
    if (e < N_EDGES) atomicAdd(&cnt[src[e]], 1);
}

__global__ __launch_bounds__(1024) void scan_kernel(const int* __restrict__ cnt,
                                                    int* __restrict__ offs) {
    __shared__ int part[1024];
    const int t = threadIdx.x;
    const int base = t * 10;
    int s = 0;
#pragma unroll
    for (int i = 0; i < 10; i++) {
        int idx = base + i;
        if (idx < N_NODES) s += cnt[idx];
    }
    part[t] = s;
    __syncthreads();
    for (int d = 1; d < 1024; d <<= 1) {
        int v = (t >= d) ? part[t - d] : 0;
        __syncthreads();
        part[t] += v;
        __syncthreads();
    }
    int run = t ? part[t - 1] : 0;
#pragma unroll
    for (int i = 0; i < 10; i++) {
        int idx = base + i;
        if (idx < N_NODES) { offs[idx] = run; run += cnt[idx]; }
    }
}

__global__ __launch_bounds__(256) void scatter_kernel(const int* __restrict__ src,
                                                      const int* __restrict__ dst,
                                                      const int* __restrict__ offs,
                                                      int* __restrict__ cur,
                                                      int* __restrict__ srcs,
                                                      int* __restrict__ dsts,
                                                      int* __restrict__ perm) {
    int e = blockIdx.x * 256 + threadIdx.x;
    if (e >= N_EDGES) return;
    int s = src[e];
    int pos = offs[s] + atomicAdd(&cur[s], 1);
    srcs[pos] = s;
    dsts[pos] = dst[e];
    perm[pos] = e;
}

// ---------------------------------------------------------------------------
// xf[idx] = f16(x[idx])
__global__ __launch_bounds__(256) void xconv(const float* __restrict__ x,
                                             f16* __restrict__ xf, int n) {
    int idx = blockIdx.x * 256 + threadIdx.x;
    if (idx < n) xf[idx] = (f16)x[idx];
}

// ---------------------------------------------------------------------------
// Bq[(k*64+o)*in + i] = f16(w2[k][i*64+o])   -- [8192, in], contiguous in i
__global__ __launch_bounds__(256) void bqconv(const float* __restrict__ w2,
                                              f16* __restrict__ Bq, int in) {
    const int k = blockIdx.x;             // 0..127
    const float* wrow = w2 + (size_t)k * (in << 6);
    const int n = in << 6;
    for (int idx = threadIdx.x; idx < n; idx += 256) {
        int i = idx >> 6, o = idx & 63;
        Bq[((size_t)(k << 6) + o) * in + i] = (f16)wrow[idx];
    }
}

// ---------------------------------------------------------------------------
// xb2[n,o] = sum_i x[n,i] * b2[i*64+o]
__global__ __launch_bounds__(256) void xb2_kernel(const float* __restrict__ x,
                                                  const float* __restrict__ b2,
                                                  float* __restrict__ xb2,
                                                  int in, int inshift) {
    __shared__ float xs[4][64];
    const int o = threadIdx.x & 63, nl = threadIdx.x >> 6;
    const int n0 = blockIdx.x * 4;
    for (int idx = threadIdx.x; idx < (4 << inshift); idx += 256) {
        int r = idx >> inshift, i = idx & (in - 1);
        xs[r][i] = (n0 + r < N_NODES) ? x[(size_t)(n0 + r) * in + i] : 0.f;
    }
    __syncthreads();
    int n = n0 + nl;
    if (n >= N_NODES) return;
    float acc = 0.f;
#pragma unroll 8
    for (int i = 0; i < in; i++) acc += xs[nl][i] * b2[i * 64 + o];
    xb2[(size_t)n * 64 + o] = acc;
}

// ---------------------------------------------------------------------------
// Y[v][C] = sum_i xf[v][i] * Bq[C][i]   M=10048, N=8192, K=IN.
// Block: 64 nodes x 512 cols, 4 waves (each 64x128). All operands in VGPRs,
// no LDS, no barriers. Write-bound by design (164 MB f16 out).
template<int IN>
__global__ __launch_bounds__(256) void ygemm_mfma(const f16* __restrict__ xf,
                                                  const f16* __restrict__ Bq,
                                                  f16* __restrict__ Y) {
    constexpr int KH = IN / 32;
    const int t = threadIdx.x;
    const int w = t >> 6, lane = t & 63;
    const int m = lane & 15, q = lane >> 4;
    const int v0 = blockIdx.x * 64;
    const int c0 = blockIdx.y * 512 + w * 128;

    v8h a[4][KH];
#pragma unroll
    for (int st = 0; st < 4; st++)
#pragma unroll
        for (int kh = 0; kh < KH; kh++)
            a[st][kh] = *(const v8h*)(xf + (size_t)(v0 + st * 16 + m) * IN + kh * 32 + q * 8);
    v8h b[8][KH];
#pragma unroll
    for (int ct = 0; ct < 8; ct++)
#pragma unroll
        for (int kh = 0; kh < KH; kh++)
            b[ct][kh] = *(const v8h*)(Bq + (size_t)(c0 + ct * 16 + m) * IN + kh * 32 + q * 8);

    v4f acc[4][8] = {};
#pragma unroll
    for (int kh = 0; kh < KH; kh++)
#pragma unroll
        for (int st = 0; st < 4; st++)
#pragma unroll
            for (int ct = 0; ct < 8; ct++)
                acc[st][ct] = __builtin_amdgcn_mfma_f32_16x16x32_f16(
                    a[st][kh], b[ct][kh], acc[st][ct], 0, 0, 0);

    // C/D: col = lane&15 (=m), row = q*4+r. Y row-major [v][8192].
#pragma unroll
    for (int st = 0; st < 4; st++)
#pragma unroll
        for (int r = 0; r < 4; r++) {
            f16* yr = Y + (size_t)(v0 + st * 16 + q * 4 + r) * NCOL + c0 + m;
#pragma unroll
            for (int ct = 0; ct < 8; ct++)
                yr[ct * 16] = (f16)acc[st][ct][r];
        }
}

// ---------------------------------------------------------------------------
// msg over sorted edges: one wave per edge. lane=(kg,og): kg covers 16 k's,
// og covers 8 o's (v8h loads). shfl_xor reduce over kg; kg==0 lanes add xb2
// and scatter to agg[dst] with atomics.
__global__ __launch_bounds__(1024) void msg_kernel(const float* __restrict__ h,
                                                   const f16* __restrict__ Y,
                                                   const int* __restrict__ srcs,
                                                   const int* __restrict__ dsts,
                                                   const int* __restrict__ perm,
                                                   const float* __restrict__ xb2,
                                                   float* __restrict__ agg) {
    int p = blockIdx.x * 16 + (threadIdx.x >> 6);
    if (p >= N_EDGES) return;
    const int lane = threadIdx.x & 63;
    const int kg = lane >> 3, og = lane & 7;
    const int s = srcs[p];
    const int eo = perm[p];
    const float4* hp = (const float4*)(h + (size_t)eo * KDIM + kg * 16);
    float4 hq0 = hp[0], hq1 = hp[1], hq2 = hp[2], hq3 = hp[3];
    const float hv[16] = {hq0.x, hq0.y, hq0.z, hq0.w, hq1.x, hq1.y, hq1.z, hq1.w,
                          hq2.x, hq2.y, hq2.z, hq2.w, hq3.x, hq3.y, hq3.z, hq3.w};
    const f16* yrow = Y + (size_t)s * NCOL + (size_t)kg * 16 * 64 + og * 8;
    float a[8] = {};
#pragma unroll
    for (int t = 0; t < 16; t++) {
        v8h yv = *(const v8h*)(yrow + (size_t)t * 64);
#pragma unroll
        for (int j = 0; j < 8; j++) a[j] += hv[t] * (float)yv[j];
    }
#pragma unroll
    for (int msk = 8; msk <= 32; msk <<= 1)
#pragma unroll
        for (int j = 0; j < 8; j++) a[j] += __shfl_xor(a[j], msk, 64);
    if (kg == 0) {
        const float* xbp = xb2 + (size_t)s * 64 + og * 8;
        const int d = dsts[p];
#pragma unroll
        for (int j = 0; j < 8; j++)
            atomicAdd(&agg[(size_t)d * 64 + og * 8 + j], a[j] + xbp[j]);
    }
}

// ---------------------------------------------------------------------------
// pre[n,o] = agg[n,o] + sum_i x[n,i]*root[i,o] + bias[o]; accumulate BN stats.
__global__ __launch_bounds__(256) void pre_stats(const float* __restrict__ agg,
                                                 const float* __restrict__ x,
                                                 const float* __restrict__ root,
                                                 const float* __restrict__ bias,
                                                 float* __restrict__ pre,
                                                 float* __restrict__ stats,
                                                 int in, int inshift) {
    __shared__ float xs[4][64];
    __shared__ float lsum[64], lsq[64];
    const int o = threadIdx.x & 63, nl = threadIdx.x >> 6;
    if (threadIdx.x < 64) { lsum[threadIdx.x] = 0.f; lsq[threadIdx.x] = 0.f; }
    const float bo = bias[o];
    for (int n0 = blockIdx.x * 4; n0 < N_NODES; n0 += gridDim.x * 4) {
        __syncthreads();
        for (int idx = threadIdx.x; idx < (4 << inshift); idx += 256) {
            int r = idx >> inshift, i = idx & (in - 1);
            if (n0 + r < N_NODES) xs[r][i] = x[(size_t)(n0 + r) * in + i];
        }
        __syncthreads();
        int n = n0 + nl;
        if (n < N_NODES) {
            float acc = agg[(size_t)n * 64 + o] + bo;
#pragma unroll 8
            for (int i = 0; i < in; i++) acc += xs[nl][i] * root[i * 64 + o];
            pre[(size_t)n * 64 + o] = acc;
            atomicAdd(&lsum[o], acc);
            atomicAdd(&lsq[o], acc * acc);
        }
    }
    __syncthreads();
    if (threadIdx.x < 64) {
        atomicAdd(&stats[threadIdx.x], lsum[threadIdx.x]);
        atomicAdd(&stats[64 + threadIdx.x], lsq[threadIdx.x]);
    }
}

// ---------------------------------------------------------------------------
// BN (batch stats, biased var) + ReLU. mode 0: store xn. mode 1: segment-max pool.
__global__ __launch_bounds__(256) void bn_apply(const float* __restrict__ pre,
                                                const float* __restrict__ stats,
                                                const float* __restrict__ gamma,
                                                const float* __restrict__ beta,
                                                float* __restrict__ xn,
                                                const int* __restrict__ batch,
                                                float* __restrict__ pooled,
                                                int mode) {
    int idx = blockIdx.x * 256 + threadIdx.x;
    if (idx >= N_NODES * 64) return;
    const int o = idx & 63, n = idx >> 6;
    const float inv = 1.f / (float)N_NODES;
    float mu = stats[o] * inv;
    float var = stats[64 + o] * inv - mu * mu;
    float sc = gamma[o] * rsqrtf(var + EPS);
    float sh = beta[o] - mu * sc;
    float v = fmaxf(pre[idx] * sc + sh, 0.f);
    if (mode == 0) xn[idx] = v;
    else atomicMax((int*)&pooled[(size_t)batch[n] * 64 + o], __float_as_int(v));
}

// ---------------------------------------------------------------------------
// out[g] = pp_b2 + relu(cat(pooled[g],u[g]) @ pp_w1 + pp_b1) @ pp_w2
__global__ __launch_bounds__(64) void final_mlp(const float* __restrict__ pooled,
                                                const float* __restrict__ u,
                                                const float* __restrict__ w1,
                                                const float* __restrict__ b1,
                                                const float* __restrict__ w2,
                                                const float* __restrict__ b2,
                                                float* __restrict__ out) {
    const int g = blockIdx.x, t = threadIdx.x;
    float acc = b1[t];
#pragma unroll 8
    for (int i = 0; i < 64; i++) acc += pooled[g * 64 + i] * w1[i * 64 + t];
#pragma unroll
    for (int j = 0; j < GIN; j++) acc += u[g * GIN + j] * w1[(64 + j) * 64 + t];
    float hv = fmaxf(acc, 0.f) * w2[t];
#pragma unroll
    for (int off = 32; off > 0; off >>= 1) hv += __shfl_down(hv, off, 64);
    if (t == 0) out[g] = hv + b2[0];
}

// ---------------------------------------------------------------------------
extern "C" void kernel_launch(void* const* d_in, const int* in_sizes, int n_in,
                              void* d_out, int out_size, void* d_ws, size_t ws_size,
                              hipStream_t stream) {
    const float* x0      = (const float*)d_in[0];
    const int*   ei      = (const int*)d_in[1];
    const int*   src     = ei;
    const int*   dst     = ei + N_EDGES;
    const float* ea      = (const float*)d_in[2];
    const int*   batch   = (const int*)d_in[3];
    const float* u       = (const float*)d_in[4];
    const float* e0w1    = (const float*)d_in[5];
    const float* e0b1    = (const float*)d_in[6];
    const float* e0w2    = (const float*)d_in[7];
    const float* e0b2    = (const float*)d_in[8];
    const float* root0   = (const float*)d_in[9];
    const float* bias0   = (const float*)d_in[10];
    const float* gamma0  = (const float*)d_in[11];
    const float* beta0   = (const float*)d_in[12];
    const float* ew1     = (const float*)d_in[13];
    const float* eb1     = (const float*)d_in[14];
    const float* ew2     = (const float*)d_in[15];
    const float* eb2     = (const float*)d_in[16];
    const float* rootl   = (const float*)d_in[17];
    const float* biasl   = (const float*)d_in[18];
    const float* gammal  = (const float*)d_in[19];
    const float* betal   = (const float*)d_in[20];
    const float* pp_w1   = (const float*)d_in[21];
    const float* pp_b1   = (const float*)d_in[22];
    const float* pp_w2   = (const float*)d_in[23];
    const float* pp_b2   = (const float*)d_in[24];

    float* ws = (float*)d_ws;
    size_t off = 0;
    float* h      = ws + off; off += (size_t)N_EDGES * KDIM;          // 6.4M
    f16*   xf     = (f16*)(ws + off); off += (size_t)NV_PAD * 64 / 2; // padded rows
    f16*   Bq     = (f16*)(ws + off); off += (size_t)NCOL * 64 / 2;
    float* xb2    = ws + off; off += (size_t)N_NODES * 64;
    float* agg    = ws + off; off += (size_t)N_NODES * 64;
    float* xa     = ws + off; off += (size_t)N_NODES * 64;
    float* xb     = ws + off; off += (size_t)N_NODES * 64;
    float* stats  = ws + off; off += 256;
    float* pooled = ws + off; off += (size_t)NG * 64;
    int*   cnt    = (int*)(ws + off); off += N_NODES;
    int*   offs   = (int*)(ws + off); off += N_NODES;
    int*   cur    = (int*)(ws + off); off += N_NODES;
    int*   srcs   = (int*)(ws + off); off += N_EDGES;
    int*   dsts   = (int*)(ws + off); off += N_EDGES;
    int*   perm   = (int*)(ws + off); off += N_EDGES;
    off = (off + 3) & ~(size_t)3;                     // 16B-align Y
    f16*   Y      = (f16*)(ws + off);                 // 10048 x 8192 f16 = 164.6 MB

    hipMemsetAsync(pooled, 0, (size_t)NG * 64 * 4, stream);
    hipMemsetAsync(cnt, 0, N_NODES * 4, stream);
    hipMemsetAsync(cur, 0, N_NODES * 4, stream);

    const int e256 = (N_EDGES + 255) / 256;
    hist_kernel<<<e256, 256, 0, stream>>>(src, cnt);
    scan_kernel<<<1, 1024, 0, stream>>>(cnt, offs);
    scatter_kernel<<<e256, 256, 0, stream>>>(src, dst, offs, cur, srcs, dsts, perm);

    struct Layer {
        const float *w1, *b1, *w2, *b2, *root, *bias, *gamma, *beta, *xin;
        float* xout; int in, inshift, mode;
    };
    Layer L[4];
    L[0] = {e0w1, e0b1, e0w2, e0b2, root0, bias0, gamma0, beta0, x0, xa, IN0, 5, 0};
    for (int l = 0; l < 3; l++) {
        const float* xin  = (l == 0) ? xa : ((l == 1) ? xb : xa);
        float*       xout = (l == 0) ? xb : ((l == 1) ? xa : nullptr);
        L[l + 1] = {ew1 + (size_t)l * EDGE_IN * KDIM, eb1 + (size_t)l * KDIM,
                    ew2 + (size_t)l * KDIM * (HID * HID), eb2 + (size_t)l * (HID * HID),
                    rootl + (size_t)l * HID * HID, biasl + (size_t)l * HID,
                    gammal + (size_t)l * HID, betal + (size_t)l * HID,
                    xin, xout, HID, 6, (l == 2) ? 1 : 0};
    }

    const int hblocks = (int)(((size_t)N_EDGES * KDIM + 255) / 256);
    const int nblocks4 = (N_NODES + 3) / 4;
    const int mblocks = (N_EDGES + 15) / 16;                 // 3125
    const int ablocks = (N_NODES * 64 + 255) / 256;

    for (int l = 0; l < 4; l++) {
        const Layer& P = L[l];
        h_kernel<<<hblocks, 256, 0, stream>>>(ea, P.w1, P.b1, h);
        xconv<<<(N_NODES * P.in + 255) / 256, 256, 0, stream>>>(P.xin, xf, N_NODES * P.in);
        bqconv<<<KDIM, 256, 0, stream>>>(P.w2, Bq, P.in);
        xb2_kernel<<<nblocks4, 256, 0, stream>>>(P.xin, P.b2, xb2, P.in, P.inshift);
        hipMemsetAsync(agg, 0, (size_t)N_NODES * 64 * 4, stream);
        hipMemsetAsync(stats, 0, 128 * 4, stream);
        if (P.in == 64)
            ygemm_mfma<64><<<dim3(NV_PAD / 64, 16), 256, 0, stream>>>(xf, Bq, Y);
        else
            ygemm_mfma<32><<<dim3(NV_PAD / 64, 16), 256, 0, stream>>>(xf, Bq, Y);
        msg_kernel<<<mblocks, 1024, 0, stream>>>(h, Y, srcs, dsts, perm, xb2, agg);
        pre_stats<<<512, 256, 0, stream>>>(agg, P.xin, P.root, P.bias, agg, stats,
                                           P.in, P.inshift);
        bn_apply<<<ablocks, 256, 0, stream>>>(agg, stats, P.gamma, P.beta, P.xout,
                                              batch, pooled, P.mode);
    }
    final_mlp<<<NG, 64, 0, stream>>>(pooled, u, pp_w1, pp_b1, pp_w2, pp_b2,
                                     (float*)d_out);
}